// Round 6
// baseline (2984.372 us; speedup 1.0000x reference)
//
#include <hip/hip_runtime.h>
#include <cstdint>
#include <cstddef>

#define B_ 4096
#define L_ 12
#define A_ 768
#define F_ 4096
#define NTRI 78

typedef __bf16 bf16x8 __attribute__((ext_vector_type(8)));
typedef float f32x4 __attribute__((ext_vector_type(4)));
typedef unsigned short u16x4 __attribute__((ext_vector_type(4)));
typedef unsigned short u16x8 __attribute__((ext_vector_type(8)));

__device__ __forceinline__ unsigned short f32_to_bf16(float f) {
  unsigned int u = __float_as_uint(f);
  u += 0x7fffu + ((u >> 16) & 1u);   // round-to-nearest-even
  return (unsigned short)(u >> 16);
}

__device__ __forceinline__ void gload_lds16(const void* g, void* l) {
  __builtin_amdgcn_global_load_lds(
      (const __attribute__((address_space(1))) void*)g,
      (__attribute__((address_space(3))) void*)l,
      16, 0, 0);
}

// ---------------------------------------------------------------------------
// prep_sx: sx[l][b][a] = (x[b][l][a] - mean[l][a]) / std[l][a]  (bf16)
// ---------------------------------------------------------------------------
__global__ __launch_bounds__(256) void prep_sx(
    const float* __restrict__ x, const float* __restrict__ mean,
    const float* __restrict__ stdv, unsigned short* __restrict__ sx) {
  size_t i4 = (size_t)blockIdx.x * 256 + threadIdx.x;
  size_t e = i4 * 4;
  if (e >= (size_t)B_ * L_ * A_) return;
  unsigned int a = (unsigned int)(e % A_);
  unsigned int t = (unsigned int)(e / A_);
  unsigned int b = t / L_;
  unsigned int l = t % L_;
  float4 xv = *(const float4*)(x + e);
  float4 mv = *(const float4*)(mean + (size_t)l * A_ + a);
  float4 sv = *(const float4*)(stdv + (size_t)l * A_ + a);
  u16x4 o;
  o.x = f32_to_bf16((xv.x - mv.x) / sv.x);
  o.y = f32_to_bf16((xv.y - mv.y) / sv.y);
  o.z = f32_to_bf16((xv.z - mv.z) / sv.z);
  o.w = f32_to_bf16((xv.w - mv.w) / sv.w);
  *(u16x4*)(sx + ((size_t)l * B_ + b) * A_ + a) = o;
}

// ---------------------------------------------------------------------------
// transpose_cvt64: per z-slice (R x C f32, row-major) -> out (C x R bf16).
// ---------------------------------------------------------------------------
__global__ __launch_bounds__(256) void transpose_cvt64(
    const float* __restrict__ in, unsigned short* __restrict__ out,
    int R, int C) {
  __shared__ float tile[64][65];
  const float* inz = in + (size_t)blockIdx.z * R * C;
  unsigned short* outz = out + (size_t)blockIdx.z * R * C;
  const int c0 = blockIdx.x * 64, r0 = blockIdx.y * 64;
  const int t = threadIdx.x;
  {
    const int c = (t & 15) * 4;
    const int rb = t >> 4;
#pragma unroll
    for (int q = 0; q < 4; ++q) {
      const int r = rb + q * 16;
      float4 v = *(const float4*)(inz + (size_t)(r0 + r) * C + (c0 + c));
      tile[r][c] = v.x; tile[r][c + 1] = v.y;
      tile[r][c + 2] = v.z; tile[r][c + 3] = v.w;
    }
  }
  __syncthreads();
  {
    const int c = t >> 2;
    const int rb = (t & 3) * 16;
#pragma unroll
    for (int h = 0; h < 2; ++h) {
      u16x8 o;
#pragma unroll
      for (int j = 0; j < 8; ++j) o[j] = f32_to_bf16(tile[rb + h * 8 + j][c]);
      *(u16x8*)(outz + (size_t)(c0 + c) * R + (r0 + rb + h * 8)) = o;
    }
  }
}

// ---------------------------------------------------------------------------
// 8-wave 256x256-tile GEMM core, BK=64, ring-2 LDS with K-HALF staging and
// COUNTED vmcnt (never 0 in steady state) — m201-faithful T3+T4.
// LDS per operand: [buf:2][khalf:2][256 rows][64 B] = 64 KiB (A+B = 128 KiB).
// Chunk swizzle within a 64B row: phys16B = g ^ (row&3); applied on the
// global source at stage time (LDS dest stays linear) and on ds_read addrs.
// Phase schedule per K-tile kt (2 barriers/phase, setprio around MFMA):
//   p1: read B,A-lo of khalf0 ; stage A-half0(kt+1) ; MFMA q1
//   p2: read A-hi khalf0      ; stage B-half0(kt+1) ; MFMA q2 ; vmcnt(4)
//   p3: read B,A-lo khalf1    ; stage A-half1(kt+1) ; MFMA q3
//   p4: read A-hi khalf1      ; stage B-half1(kt+1) ; MFMA q4 ; vmcnt(4)
// vmcnt(4) at p2-end proves half1(kt) landed (4 newer loads outstanding);
// at p4-end proves half0(kt+1) landed. Drain to 0 only on the last tile.
// Half-reuse safety: half X of buf^1 was last ds_read >=3 barriers before
// any stage into it (reads retire before their consuming MFMA cluster).
// ---------------------------------------------------------------------------
template <class KOffA, class KOffB>
__device__ __forceinline__ void gemm_core64(
    int KT, char* AS, char* BS,
    const char* gA0, const char* gB0, int ldA, int ldB,
    int w, int wr, int wc, int lane,
    KOffA koffA, KOffB koffB, f32x4 (&acc)[8][4]) {
  const int g = lane >> 4;
  const int fr = lane & 15;
  const uint32_t swz = (uint32_t)((g ^ (fr & 3)) * 16);
  const uint32_t aBase = (uint32_t)(wr * 128 + fr) * 64 + swz;
  const uint32_t bBase = (uint32_t)(wc * 64 + fr) * 64 + swz;

  auto stageA = [&](int kt, int h) {
    const uint32_t off = koffA(kt) + (uint32_t)(h * 64);
    char* d = AS + ((kt & 1) << 15) + (h << 14) + (w << 10);
#pragma unroll
    for (int q = 0; q < 2; ++q)
      gload_lds16(gA0 + off + (uint32_t)((q * 8 + w) * 16) * (uint32_t)ldA,
                  d + q * 8192);
  };
  auto stageB = [&](int kt, int h) {
    const uint32_t off = koffB(kt) + (uint32_t)(h * 64);
    char* d = BS + ((kt & 1) << 15) + (h << 14) + (w << 10);
#pragma unroll
    for (int q = 0; q < 2; ++q)
      gload_lds16(gB0 + off + (uint32_t)((q * 8 + w) * 16) * (uint32_t)ldB,
                  d + q * 8192);
  };

  // prologue: stage all 4 halves of tile 0; wait for half0 (A1,B1 in flight)
  stageA(0, 0);
  stageB(0, 0);
  stageA(0, 1);
  stageB(0, 1);
  asm volatile("s_waitcnt vmcnt(4)" ::: "memory");
  __builtin_amdgcn_s_barrier();

  bf16x8 bk[4], aA[4], aB[4];
  for (int kt = 0; kt < KT; ++kt) {
    const char* Ab = AS + ((kt & 1) << 15);
    const char* Bb = BS + ((kt & 1) << 15);
    const bool more = (kt + 1 < KT);
    // ---------------- phase 1: khalf0, B + A-lo ----------------
#pragma unroll
    for (int ni = 0; ni < 4; ++ni)
      bk[ni] = *(const bf16x8*)(Bb + bBase + ni * 1024);
#pragma unroll
    for (int mi = 0; mi < 4; ++mi)
      aA[mi] = *(const bf16x8*)(Ab + aBase + mi * 1024);
    if (more) stageA(kt + 1, 0);
    asm volatile("" ::: "memory");
    __builtin_amdgcn_s_barrier();
    __builtin_amdgcn_s_setprio(1);
#pragma unroll
    for (int mi = 0; mi < 4; ++mi)
#pragma unroll
      for (int ni = 0; ni < 4; ++ni)
        acc[mi][ni] = __builtin_amdgcn_mfma_f32_16x16x32_bf16(
            aA[mi], bk[ni], acc[mi][ni], 0, 0, 0);
    __builtin_amdgcn_s_setprio(0);
    asm volatile("" ::: "memory");
    __builtin_amdgcn_s_barrier();
    // ---------------- phase 2: khalf0, A-hi ----------------
#pragma unroll
    for (int mi = 0; mi < 4; ++mi)
      aB[mi] = *(const bf16x8*)(Ab + aBase + (4 + mi) * 1024);
    if (more) stageB(kt + 1, 0);
    asm volatile("" ::: "memory");
    __builtin_amdgcn_s_barrier();
    __builtin_amdgcn_s_setprio(1);
#pragma unroll
    for (int mi = 0; mi < 4; ++mi)
#pragma unroll
      for (int ni = 0; ni < 4; ++ni)
        acc[mi + 4][ni] = __builtin_amdgcn_mfma_f32_16x16x32_bf16(
            aB[mi], bk[ni], acc[mi + 4][ni], 0, 0, 0);
    __builtin_amdgcn_s_setprio(0);
    if (more) { asm volatile("s_waitcnt vmcnt(4)" ::: "memory"); }
    else      { asm volatile("s_waitcnt vmcnt(0)" ::: "memory"); }
    __builtin_amdgcn_s_barrier();
    // ---------------- phase 3: khalf1, B + A-lo ----------------
#pragma unroll
    for (int ni = 0; ni < 4; ++ni)
      bk[ni] = *(const bf16x8*)(Bb + 16384 + bBase + ni * 1024);
#pragma unroll
    for (int mi = 0; mi < 4; ++mi)
      aA[mi] = *(const bf16x8*)(Ab + 16384 + aBase + mi * 1024);
    if (more) stageA(kt + 1, 1);
    asm volatile("" ::: "memory");
    __builtin_amdgcn_s_barrier();
    __builtin_amdgcn_s_setprio(1);
#pragma unroll
    for (int mi = 0; mi < 4; ++mi)
#pragma unroll
      for (int ni = 0; ni < 4; ++ni)
        acc[mi][ni] = __builtin_amdgcn_mfma_f32_16x16x32_bf16(
            aA[mi], bk[ni], acc[mi][ni], 0, 0, 0);
    __builtin_amdgcn_s_setprio(0);
    asm volatile("" ::: "memory");
    __builtin_amdgcn_s_barrier();
    // ---------------- phase 4: khalf1, A-hi ----------------
#pragma unroll
    for (int mi = 0; mi < 4; ++mi)
      aB[mi] = *(const bf16x8*)(Ab + 16384 + aBase + (4 + mi) * 1024);
    if (more) stageB(kt + 1, 1);
    asm volatile("" ::: "memory");
    __builtin_amdgcn_s_barrier();
    __builtin_amdgcn_s_setprio(1);
#pragma unroll
    for (int mi = 0; mi < 4; ++mi)
#pragma unroll
      for (int ni = 0; ni < 4; ++ni)
        acc[mi + 4][ni] = __builtin_amdgcn_mfma_f32_16x16x32_bf16(
            aB[mi], bk[ni], acc[mi + 4][ni], 0, 0, 0);
    __builtin_amdgcn_s_setprio(0);
    if (more) { asm volatile("s_waitcnt vmcnt(4)" ::: "memory"); }
    __builtin_amdgcn_s_barrier();
  }
}

// ---------------------------------------------------------------------------
// Encoder: enc[b,l,f] = sum_a sx[l,b,a] * WencT[l,f,a]; act = JumpReLU(enc)
// grid 3072 = 12 layers x (16 m x 16 n), chunked XCD swizzle (3072 % 8 == 0)
// ---------------------------------------------------------------------------
__global__ __launch_bounds__(512, 2) void enc_gemm8(
    const unsigned short* __restrict__ sxT,   // (L,B,A)
    const unsigned short* __restrict__ wT,    // (L,F,A)
    const float* __restrict__ theta,          // (L,F)
    float* __restrict__ enc_out,              // (B,L,F)
    unsigned short* __restrict__ act)         // (L,B,F)
{
  extern __shared__ __align__(16) char lds[];
  char* AS = lds;
  char* BS = lds + 65536;
  const int b = blockIdx.x;
  const int wg = (b & 7) * 384 + (b >> 3);
  const int l = wg >> 8;
  const int blk = wg & 255;
  const int m0 = (blk & 15) * 256;
  const int n0 = (blk >> 4) * 256;
  const int tid = threadIdx.x;
  const int w = tid >> 6, lane = tid & 63;
  const int wr = w >> 2, wc = w & 3;
  const int srow2 = lane >> 2;
  const int scol2 = ((lane & 3) ^ (srow2 & 3)) * 16;

  const char* gA0 = (const char*)sxT +
      ((size_t)l * B_ + m0 + srow2) * (A_ * 2) + scol2;
  const char* gB0 = (const char*)wT +
      ((size_t)l * F_ + n0 + srow2) * (A_ * 2) + scol2;

  f32x4 acc[8][4] = {};
  auto koffA = [](int kt) { return (uint32_t)kt * 128u; };
  auto koffB = [](int kt) { return (uint32_t)kt * 128u; };
  gemm_core64(A_ / 64, AS, BS, gA0, gB0, A_ * 2, A_ * 2, w, wr, wc, lane,
              koffA, koffB, acc);

  const int g = lane >> 4, fr = lane & 15;
#pragma unroll
  for (int ni = 0; ni < 4; ++ni) {
    const int gcol = n0 + wc * 64 + ni * 16 + fr;
    const float th = theta[(size_t)l * F_ + gcol];
#pragma unroll
    for (int mi = 0; mi < 8; ++mi) {
      const int growb = m0 + wr * 128 + mi * 16 + g * 4;
#pragma unroll
      for (int jj = 0; jj < 4; ++jj) {
        const float v = acc[mi][ni][jj];
        const size_t grow = (size_t)(growb + jj);
        enc_out[(grow * L_ + l) * F_ + gcol] = v;
        act[((size_t)l * B_ + grow) * F_ + gcol] =
            (v > th) ? f32_to_bf16(v) : (unsigned short)0;
      }
    }
  }
}

// ---------------------------------------------------------------------------
// Decoder: logits[b,i,a] = sum_{l<=i} sum_f act[l,b,f] * WdecT[tri(i,l),a,f]
// grid 576, heavy layers first (greedy LPT-ish balance).
// ---------------------------------------------------------------------------
__global__ __launch_bounds__(512, 2) void dec_gemm8(
    const unsigned short* __restrict__ act,    // (L,B,F)
    const unsigned short* __restrict__ wdecT,  // (NTRI,A,F)
    float* __restrict__ logits)                // (B,L,A)
{
  extern __shared__ __align__(16) char lds[];
  char* AS = lds;
  char* BS = lds + 65536;
  const int b = blockIdx.x;
  const int z = b / 48;            // 0..11, heavy first
  const int blk = b - z * 48;      // 0..47
  const int i = 11 - z;
  const int m0 = (blk & 15) * 256;
  const int n0 = (blk >> 4) * 256; // {0,256,512}
  const int triBase = i * (i + 1) / 2;
  const int KT = (i + 1) * 64;
  const int tid = threadIdx.x;
  const int w = tid >> 6, lane = tid & 63;
  const int wr = w >> 2, wc = w & 3;
  const int srow2 = lane >> 2;
  const int scol2 = ((lane & 3) ^ (srow2 & 3)) * 16;

  const char* gA0 =
      (const char*)act + ((size_t)(m0 + srow2)) * (F_ * 2) + scol2;
  const char* gB0 = (const char*)wdecT +
      ((size_t)(triBase * A_ + n0 + srow2)) * (F_ * 2) + scol2;

  f32x4 acc[8][4] = {};
  auto koffA = [](int kt) {
    return (uint32_t)(kt >> 6) * (uint32_t)(B_ * F_ * 2) +
           (uint32_t)(kt & 63) * 128u;
  };
  auto koffB = [](int kt) {
    return (uint32_t)(kt >> 6) * (uint32_t)(A_ * F_ * 2) +
           (uint32_t)(kt & 63) * 128u;
  };
  gemm_core64(KT, AS, BS, gA0, gB0, F_ * 2, F_ * 2, w, wr, wc, lane,
              koffA, koffB, acc);

  const int g = lane >> 4, fr = lane & 15;
#pragma unroll
  for (int mi = 0; mi < 8; ++mi) {
    const int growb = m0 + wr * 128 + mi * 16 + g * 4;
#pragma unroll
    for (int ni = 0; ni < 4; ++ni) {
      const int gcol = n0 + wc * 64 + ni * 16 + fr;
#pragma unroll
      for (int jj = 0; jj < 4; ++jj)
        logits[((size_t)(growb + jj) * L_ + i) * A_ + gcol] = acc[mi][ni][jj];
    }
  }
}

// ---------------------------------------------------------------------------
extern "C" void kernel_launch(void* const* d_in, const int* in_sizes, int n_in,
                              void* d_out, int out_size, void* d_ws,
                              size_t ws_size, hipStream_t stream) {
  (void)in_sizes; (void)n_in; (void)out_size; (void)ws_size;
  const float* x = (const float*)d_in[0];
  const float* mean = (const float*)d_in[1];
  const float* stdv = (const float*)d_in[2];
  const float* Wenc = (const float*)d_in[3];
  const float* theta = (const float*)d_in[4];
  const float* Wdec = (const float*)d_in[5];

  float* logits = (float*)d_out;
  float* enc = (float*)d_out + (size_t)B_ * L_ * A_;

  char* ws = (char*)d_ws;
  const size_t actBytes = (size_t)L_ * B_ * F_ * 2;      // 402.7 MB
  const size_t sxBytes = (size_t)L_ * B_ * A_ * 2;       // 75.5 MB
  unsigned short* act = (unsigned short*)ws;
  unsigned short* sx = (unsigned short*)(ws + actBytes);
  unsigned short* wencT = (unsigned short*)(ws + actBytes + sxBytes);
  // W_dec^T only needed after the encoder; alias it over sx/wencT.
  unsigned short* wdecT = (unsigned short*)(ws + actBytes);

  hipFuncSetAttribute((const void*)enc_gemm8,
                      hipFuncAttributeMaxDynamicSharedMemorySize, 131072);
  hipFuncSetAttribute((const void*)dec_gemm8,
                      hipFuncAttributeMaxDynamicSharedMemorySize, 131072);

  prep_sx<<<(B_ * L_ * A_ / 4 + 255) / 256, 256, 0, stream>>>(x, mean, stdv, sx);
  transpose_cvt64<<<dim3(F_ / 64, A_ / 64, L_), 256, 0, stream>>>(
      Wenc, wencT, A_, F_);
  enc_gemm8<<<3072, 512, 131072, stream>>>(sx, wencT, theta, enc, act);
  transpose_cvt64<<<dim3(A_ / 64, F_ / 64, NTRI), 256, 0, stream>>>(
      Wdec, wdecT, F_, A_);
  dec_gemm8<<<576, 512, 131072, stream>>>(act, wdecT, logits);
}

// Round 7
// 2940.056 us; speedup vs baseline: 1.0151x; 1.0151x over previous
//
#include <hip/hip_runtime.h>
#include <cstdint>
#include <cstddef>

#define B_ 4096
#define L_ 12
#define A_ 768
#define F_ 4096
#define NTRI 78

typedef __bf16 bf16x8 __attribute__((ext_vector_type(8)));
typedef float f32x4 __attribute__((ext_vector_type(4)));
typedef unsigned short u16x4 __attribute__((ext_vector_type(4)));
typedef unsigned short u16x8 __attribute__((ext_vector_type(8)));

__device__ __forceinline__ unsigned short f32_to_bf16(float f) {
  unsigned int u = __float_as_uint(f);
  u += 0x7fffu + ((u >> 16) & 1u);   // round-to-nearest-even
  return (unsigned short)(u >> 16);
}

__device__ __forceinline__ void gload_lds16(const void* g, void* l) {
  __builtin_amdgcn_global_load_lds(
      (const __attribute__((address_space(1))) void*)g,
      (__attribute__((address_space(3))) void*)l,
      16, 0, 0);
}

// ---------------------------------------------------------------------------
// prep_sx: sx[l][b][a] = (x[b][l][a] - mean[l][a]) / std[l][a]  (bf16)
// ---------------------------------------------------------------------------
__global__ __launch_bounds__(256) void prep_sx(
    const float* __restrict__ x, const float* __restrict__ mean,
    const float* __restrict__ stdv, unsigned short* __restrict__ sx) {
  size_t i4 = (size_t)blockIdx.x * 256 + threadIdx.x;
  size_t e = i4 * 4;
  if (e >= (size_t)B_ * L_ * A_) return;
  unsigned int a = (unsigned int)(e % A_);
  unsigned int t = (unsigned int)(e / A_);
  unsigned int b = t / L_;
  unsigned int l = t % L_;
  float4 xv = *(const float4*)(x + e);
  float4 mv = *(const float4*)(mean + (size_t)l * A_ + a);
  float4 sv = *(const float4*)(stdv + (size_t)l * A_ + a);
  u16x4 o;
  o.x = f32_to_bf16((xv.x - mv.x) / sv.x);
  o.y = f32_to_bf16((xv.y - mv.y) / sv.y);
  o.z = f32_to_bf16((xv.z - mv.z) / sv.z);
  o.w = f32_to_bf16((xv.w - mv.w) / sv.w);
  *(u16x4*)(sx + ((size_t)l * B_ + b) * A_ + a) = o;
}

// ---------------------------------------------------------------------------
// transpose_cvt64: per z-slice (R x C f32, row-major) -> out (C x R bf16).
// ---------------------------------------------------------------------------
__global__ __launch_bounds__(256) void transpose_cvt64(
    const float* __restrict__ in, unsigned short* __restrict__ out,
    int R, int C) {
  __shared__ float tile[64][65];
  const float* inz = in + (size_t)blockIdx.z * R * C;
  unsigned short* outz = out + (size_t)blockIdx.z * R * C;
  const int c0 = blockIdx.x * 64, r0 = blockIdx.y * 64;
  const int t = threadIdx.x;
  {
    const int c = (t & 15) * 4;
    const int rb = t >> 4;
#pragma unroll
    for (int q = 0; q < 4; ++q) {
      const int r = rb + q * 16;
      float4 v = *(const float4*)(inz + (size_t)(r0 + r) * C + (c0 + c));
      tile[r][c] = v.x; tile[r][c + 1] = v.y;
      tile[r][c + 2] = v.z; tile[r][c + 3] = v.w;
    }
  }
  __syncthreads();
  {
    const int c = t >> 2;
    const int rb = (t & 3) * 16;
#pragma unroll
    for (int h = 0; h < 2; ++h) {
      u16x8 o;
#pragma unroll
      for (int j = 0; j < 8; ++j) o[j] = f32_to_bf16(tile[rb + h * 8 + j][c]);
      *(u16x8*)(outz + (size_t)(c0 + c) * R + (r0 + rb + h * 8)) = o;
    }
  }
}

// ---------------------------------------------------------------------------
// 8-wave 256x256-tile GEMM core, BK=32, ring-4 LDS, prefetch distance 3,
// 2 phases per K-tile (T3), counted vmcnt (T4), setprio clusters (T5).
// LDS per operand: 4 slots x [256 rows][32 k] bf16 (64 B rows) = 64 KiB.
// Chunk swizzle (round-4-verified, 0 conflicts): within a 64 B row split in
// four 16 B chunks, phys_chunk = logical_chunk ^ ((row>>1)&3). Applied on the
// global source at stage time (LDS dest stays linear) and on ds_read addrs
// (lanes fr and fr+8 share a bank -> 2-way, which is free).
// Schedule per K-tile kt:
//   p1: read B ni0-3 + A mi0-3 (8 ds_read) ; stage A(kt+3) ; barrier ;
//       setprio(1) ; 16 MFMA lo ; setprio(0) ; barrier
//   p2: read A mi4-7 (4 ds_read) ; stage B(kt+3) ; barrier ;
//       setprio(1) ; 16 MFMA hi ; setprio(0) ; vmcnt(8) ; barrier
// vmcnt ledger: 4 loads/wave/tile; at p2-end the 8 newest = tiles kt+2,kt+3
// -> vmcnt(8) publishes tile kt+1; tail kt=KT-3 -> vmcnt(4), kt=KT-2 -> 0.
// Slot-reuse: slot (kt+3)&3 == (kt-1)&3; tile kt-1's reads retired before its
// closing barrier, which precedes every wave's stage issue of kt+3.
// ---------------------------------------------------------------------------
template <class KOffA, class KOffB>
__device__ __forceinline__ void gemm_core32(
    int KT, char* AS, char* BS,
    const char* gA0s, const char* gB0s,   // per-lane staging base addrs
    int ldA, int ldB,                     // global row strides in bytes
    int w, int wr, int wc, int lane,
    KOffA koffA, KOffB koffB, f32x4 (&acc)[8][4]) {
  const int g = lane >> 4;
  const int fr = lane & 15;
  const uint32_t ssr = (uint32_t)((g ^ ((fr >> 1) & 3)) * 16);
  const uint32_t aBase = (uint32_t)(wr * 128 + fr) * 64 + ssr;
  const uint32_t bBase = (uint32_t)(wc * 64 + fr) * 64 + ssr;

  auto stageA = [&](int kt) {
    const uint32_t off = koffA(kt);
    char* d = AS + (kt & 3) * 16384 + (w << 10);
    gload_lds16(gA0s + off, d);
    gload_lds16(gA0s + off + 128u * (uint32_t)ldA, d + 8192);
  };
  auto stageB = [&](int kt) {
    const uint32_t off = koffB(kt);
    char* d = BS + (kt & 3) * 16384 + (w << 10);
    gload_lds16(gB0s + off, d);
    gload_lds16(gB0s + off + 128u * (uint32_t)ldB, d + 8192);
  };

  // prologue: stage tiles 0,1,2 (12 loads); vmcnt(8) -> tile 0 landed.
  stageA(0); stageB(0);
  stageA(1); stageB(1);
  stageA(2); stageB(2);
  asm volatile("s_waitcnt vmcnt(8)" ::: "memory");
  __builtin_amdgcn_s_barrier();

  bf16x8 bk[4], aA[4], aB[4];
  for (int kt = 0; kt < KT; ++kt) {
    const char* Ab = AS + (kt & 3) * 16384;
    const char* Bb = BS + (kt & 3) * 16384;
    const bool more = (kt + 3 < KT);
    // ---------------- phase 1 ----------------
#pragma unroll
    for (int ni = 0; ni < 4; ++ni)
      bk[ni] = *(const bf16x8*)(Bb + bBase + ni * 1024);
#pragma unroll
    for (int mi = 0; mi < 4; ++mi)
      aA[mi] = *(const bf16x8*)(Ab + aBase + mi * 1024);
    if (more) stageA(kt + 3);
    asm volatile("" ::: "memory");
    __builtin_amdgcn_s_barrier();
    __builtin_amdgcn_s_setprio(1);
#pragma unroll
    for (int mi = 0; mi < 4; ++mi)
#pragma unroll
      for (int ni = 0; ni < 4; ++ni)
        acc[mi][ni] = __builtin_amdgcn_mfma_f32_16x16x32_bf16(
            aA[mi], bk[ni], acc[mi][ni], 0, 0, 0);
    __builtin_amdgcn_s_setprio(0);
    asm volatile("" ::: "memory");
    __builtin_amdgcn_s_barrier();
    // ---------------- phase 2 ----------------
#pragma unroll
    for (int mi = 0; mi < 4; ++mi)
      aB[mi] = *(const bf16x8*)(Ab + aBase + (4 + mi) * 1024);
    if (more) stageB(kt + 3);
    asm volatile("" ::: "memory");
    __builtin_amdgcn_s_barrier();
    __builtin_amdgcn_s_setprio(1);
#pragma unroll
    for (int mi = 0; mi < 4; ++mi)
#pragma unroll
      for (int ni = 0; ni < 4; ++ni)
        acc[mi + 4][ni] = __builtin_amdgcn_mfma_f32_16x16x32_bf16(
            aB[mi], bk[ni], acc[mi + 4][ni], 0, 0, 0);
    __builtin_amdgcn_s_setprio(0);
    if (more)                { asm volatile("s_waitcnt vmcnt(8)" ::: "memory"); }
    else if (kt + 2 < KT)    { asm volatile("s_waitcnt vmcnt(4)" ::: "memory"); }
    else if (kt + 1 < KT)    { asm volatile("s_waitcnt vmcnt(0)" ::: "memory"); }
    __builtin_amdgcn_s_barrier();
  }
}

// ---------------------------------------------------------------------------
// Encoder: enc[b,l,f] = sum_a sx[l,b,a] * WencT[l,f,a]; act = JumpReLU(enc)
// grid 3072 = 12 layers x (16 m x 16 n), chunked XCD swizzle (3072 % 8 == 0)
// ---------------------------------------------------------------------------
__global__ __launch_bounds__(512, 2) void enc_gemm8(
    const unsigned short* __restrict__ sxT,   // (L,B,A)
    const unsigned short* __restrict__ wT,    // (L,F,A)
    const float* __restrict__ theta,          // (L,F)
    float* __restrict__ enc_out,              // (B,L,F)
    unsigned short* __restrict__ act)         // (L,B,F)
{
  extern __shared__ __align__(16) char lds[];
  char* AS = lds;
  char* BS = lds + 65536;
  const int b = blockIdx.x;
  const int wg = (b & 7) * 384 + (b >> 3);
  const int l = wg >> 8;
  const int blk = wg & 255;
  const int m0 = (blk & 15) * 256;
  const int n0 = (blk >> 4) * 256;
  const int tid = threadIdx.x;
  const int w = tid >> 6, lane = tid & 63;
  const int wr = w >> 2, wc = w & 3;
  // staging lane geometry: row = q*128 + w*16 + (lane>>2);
  // phys chunk (lane&3) holds global chunk (lane&3)^((row>>1)&3), and
  // (row>>1)&3 == (lane>>3)&3 for these rows.
  const int srowS = w * 16 + (lane >> 2);
  const int chnkS = ((lane & 3) ^ ((lane >> 3) & 3)) * 16;

  const char* gA0s = (const char*)sxT +
      ((size_t)l * B_ + m0 + srowS) * (A_ * 2) + chnkS;
  const char* gB0s = (const char*)wT +
      ((size_t)l * F_ + n0 + srowS) * (A_ * 2) + chnkS;

  f32x4 acc[8][4] = {};
  auto koffA = [](int kt) { return (uint32_t)kt * 64u; };
  auto koffB = [](int kt) { return (uint32_t)kt * 64u; };
  gemm_core32(A_ / 32, AS, BS, gA0s, gB0s, A_ * 2, A_ * 2, w, wr, wc, lane,
              koffA, koffB, acc);

  const int g = lane >> 4, fr = lane & 15;
#pragma unroll
  for (int ni = 0; ni < 4; ++ni) {
    const int gcol = n0 + wc * 64 + ni * 16 + fr;
    const float th = theta[(size_t)l * F_ + gcol];
#pragma unroll
    for (int mi = 0; mi < 8; ++mi) {
      const int growb = m0 + wr * 128 + mi * 16 + g * 4;
#pragma unroll
      for (int jj = 0; jj < 4; ++jj) {
        const float v = acc[mi][ni][jj];
        const size_t grow = (size_t)(growb + jj);
        enc_out[(grow * L_ + l) * F_ + gcol] = v;
        act[((size_t)l * B_ + grow) * F_ + gcol] =
            (v > th) ? f32_to_bf16(v) : (unsigned short)0;
      }
    }
  }
}

// ---------------------------------------------------------------------------
// Decoder: logits[b,i,a] = sum_{l<=i} sum_f act[l,b,f] * WdecT[tri(i,l),a,f]
// grid 576, heavy layers first (greedy balance via dynamic block scheduling).
// ---------------------------------------------------------------------------
__global__ __launch_bounds__(512, 2) void dec_gemm8(
    const unsigned short* __restrict__ act,    // (L,B,F)
    const unsigned short* __restrict__ wdecT,  // (NTRI,A,F)
    float* __restrict__ logits)                // (B,L,A)
{
  extern __shared__ __align__(16) char lds[];
  char* AS = lds;
  char* BS = lds + 65536;
  const int b = blockIdx.x;
  const int z = b / 48;            // 0..11, heavy first
  const int blk = b - z * 48;      // 0..47
  const int i = 11 - z;
  const int m0 = (blk & 15) * 256;
  const int n0 = (blk >> 4) * 256; // {0,256,512}
  const int triBase = i * (i + 1) / 2;
  const int KT = (i + 1) * 128;    // BK=32 tiles
  const int tid = threadIdx.x;
  const int w = tid >> 6, lane = tid & 63;
  const int wr = w >> 2, wc = w & 3;
  const int srowS = w * 16 + (lane >> 2);
  const int chnkS = ((lane & 3) ^ ((lane >> 3) & 3)) * 16;

  const char* gA0s =
      (const char*)act + ((size_t)(m0 + srowS)) * (F_ * 2) + chnkS;
  const char* gB0s = (const char*)wdecT +
      ((size_t)(triBase * A_ + n0 + srowS)) * (F_ * 2) + chnkS;

  f32x4 acc[8][4] = {};
  auto koffA = [](int kt) {
    return (uint32_t)(kt >> 7) * (uint32_t)(B_ * F_ * 2) +
           (uint32_t)(kt & 127) * 64u;
  };
  auto koffB = [](int kt) {
    return (uint32_t)(kt >> 7) * (uint32_t)(A_ * F_ * 2) +
           (uint32_t)(kt & 127) * 64u;
  };
  gemm_core32(KT, AS, BS, gA0s, gB0s, F_ * 2, F_ * 2, w, wr, wc, lane,
              koffA, koffB, acc);

  const int g = lane >> 4, fr = lane & 15;
#pragma unroll
  for (int mi = 0; mi < 8; ++mi) {
    const int growb = m0 + wr * 128 + mi * 16 + g * 4;
#pragma unroll
    for (int ni = 0; ni < 4; ++ni) {
      const int gcol = n0 + wc * 64 + ni * 16 + fr;
#pragma unroll
      for (int jj = 0; jj < 4; ++jj)
        logits[((size_t)(growb + jj) * L_ + i) * A_ + gcol] = acc[mi][ni][jj];
    }
  }
}

// ---------------------------------------------------------------------------
extern "C" void kernel_launch(void* const* d_in, const int* in_sizes, int n_in,
                              void* d_out, int out_size, void* d_ws,
                              size_t ws_size, hipStream_t stream) {
  (void)in_sizes; (void)n_in; (void)out_size; (void)ws_size;
  const float* x = (const float*)d_in[0];
  const float* mean = (const float*)d_in[1];
  const float* stdv = (const float*)d_in[2];
  const float* Wenc = (const float*)d_in[3];
  const float* theta = (const float*)d_in[4];
  const float* Wdec = (const float*)d_in[5];

  float* logits = (float*)d_out;
  float* enc = (float*)d_out + (size_t)B_ * L_ * A_;

  char* ws = (char*)d_ws;
  const size_t actBytes = (size_t)L_ * B_ * F_ * 2;      // 402.7 MB
  const size_t sxBytes = (size_t)L_ * B_ * A_ * 2;       // 75.5 MB
  unsigned short* act = (unsigned short*)ws;
  unsigned short* sx = (unsigned short*)(ws + actBytes);
  unsigned short* wencT = (unsigned short*)(ws + actBytes + sxBytes);
  // W_dec^T only needed after the encoder; alias it over sx/wencT.
  unsigned short* wdecT = (unsigned short*)(ws + actBytes);

  hipFuncSetAttribute((const void*)enc_gemm8,
                      hipFuncAttributeMaxDynamicSharedMemorySize, 131072);
  hipFuncSetAttribute((const void*)dec_gemm8,
                      hipFuncAttributeMaxDynamicSharedMemorySize, 131072);

  prep_sx<<<(B_ * L_ * A_ / 4 + 255) / 256, 256, 0, stream>>>(x, mean, stdv, sx);
  transpose_cvt64<<<dim3(F_ / 64, A_ / 64, L_), 256, 0, stream>>>(
      Wenc, wencT, A_, F_);
  enc_gemm8<<<3072, 512, 131072, stream>>>(sx, wencT, theta, enc, act);
  transpose_cvt64<<<dim3(A_ / 64, F_ / 64, NTRI), 256, 0, stream>>>(
      Wdec, wdecT, F_, A_);
  dec_gemm8<<<576, 512, 131072, stream>>>(act, wdecT, logits);
}